// Round 2
// baseline (18221.355 us; speedup 1.0000x reference)
//
#include <hip/hip_runtime.h>
#include <hip/hip_cooperative_groups.h>

namespace cg = cooperative_groups;

#define T_STEPS 512
#define B_ROWS  64
#define F_DIM   256
#define U_DIM   1024
#define G3      3072   // 3*U
#define KTOT    1280   // F + U
#define LDSK    1288   // KTOT + 8 bf16 pad -> row stride 2576B (2-way bank pattern, free)
#define LDS_BYTES (3 * 16 * LDSK * 2)

typedef __bf16 bf16x8 __attribute__((ext_vector_type(8)));
typedef float  f32x4  __attribute__((ext_vector_type(4)));

__device__ __forceinline__ float sigmoidf_(float v) {
    return 1.f / (1.f + __expf(-v));
}
__device__ __forceinline__ float tanhf_(float v) {
    float e2 = __expf(2.f * v);
    return 1.f - 2.f / (e2 + 1.f);
}

// ---------------------------------------------------------------------------
// Transpose + cvt: src [Kdim][3072] f32  ->  dst [3072][Kdim] bf16
// ---------------------------------------------------------------------------
__global__ __launch_bounds__(256) void transpose_cvt_kernel(
    const float* __restrict__ src, __bf16* __restrict__ dst, int Kdim)
{
    __shared__ float tile[32][33];
    const int n0 = blockIdx.x * 32;
    const int k0 = blockIdx.y * 32;
    const int j  = threadIdx.x & 31;
    const int i0 = threadIdx.x >> 5;   // 0..7
#pragma unroll
    for (int s = 0; s < 4; ++s) {
        int i = i0 * 4 + s;
        tile[i][j] = src[(size_t)(k0 + i) * G3 + n0 + j];
    }
    __syncthreads();
#pragma unroll
    for (int s = 0; s < 4; ++s) {
        int i = i0 * 4 + s;
        dst[(size_t)(n0 + i) * Kdim + k0 + j] = (__bf16)tile[j][i];
    }
}

// ---------------------------------------------------------------------------
// Persistent GRU. Grid = 256 blocks x 64 threads (1 wave each, 1 block/CU).
// Block bid: coltile c = bid & 63 (16 u's), rowtile rt = bid >> 6 (16 rows).
// Weight slice (3 gates x 16 u x 1280 k, bf16) lives in LDS for all 512 steps.
// A-frag: lane holds A[row=l&15][k=(l>>4)*8+e];  B-frag: B[k][col=l&15] from
// LDS rows;  C/D: col=l&15, row=(l>>4)*4+j.  f32 carry stays in registers.
// ---------------------------------------------------------------------------
template<bool BF16H>
__global__ __launch_bounds__(64, 1) void gru_persistent(
    const float* __restrict__ x,       // [64][512][256] f32
    const float* __restrict__ hidden,  // [64][1024] f32
    const float* __restrict__ bias,    // [2][3072] f32
    const __bf16* __restrict__ Kt,     // [3072][256]
    const __bf16* __restrict__ Rt,     // [3072][1024]
    __bf16* __restrict__ hbufA,        // [64][1024] (used iff BF16H)
    __bf16* __restrict__ hbufB,
    float* __restrict__ out)           // [64][512][1024] f32 (+ state tail)
{
    extern __shared__ __bf16 wlds[];   // [3*16][LDSK]
    const int lane = threadIdx.x & 63;
    const int rc   = lane & 15;
    const int kg   = lane >> 4;
    const int bid  = blockIdx.x;
    const int c    = bid & 63;
    const int rt   = bid >> 6;
    const int u    = (c << 4) + rc;
    const int row0 = rt << 4;

    // ---- stage weight slice into LDS (once). Row rrow = g*16+ul holds
    // [Kt_row(256) | Rt_row(1024)] for gate g, local col ul. ----
    for (int i = lane; i < 48 * 160; i += 64) {
        const int rrow = i / 160;
        const int ch   = i - rrow * 160;          // 16B chunk index
        const int g    = rrow >> 4;
        const int ul   = rrow & 15;
        const int gu   = g * U_DIM + (c << 4) + ul;
        bf16x8 v;
        if (ch < 32) v = *(const bf16x8*)(Kt + (size_t)gu * F_DIM + ch * 8);
        else         v = *(const bf16x8*)(Rt + (size_t)gu * U_DIM + (ch - 32) * 8);
        *(bf16x8*)(wlds + rrow * LDSK + ch * 8) = v;
    }
    __syncthreads();

    // ---- init bf16 h buffer from hidden (block b inits row b) ----
    if (BF16H && bid < B_ROWS) {
        const float* hr = hidden + (size_t)bid * U_DIM;
        __bf16* dr = hbufA + (size_t)bid * U_DIM;
        for (int i = lane; i < U_DIM; i += 64) dr[i] = (__bf16)hr[i];
    }

    cg::grid_group grid = cg::this_grid();
    grid.sync();

    // ---- per-thread invariants ----
    float hprev[4];
#pragma unroll
    for (int j = 0; j < 4; ++j)
        hprev[j] = hidden[(size_t)(row0 + (kg << 2) + j) * U_DIM + u];

    const float bz_ = bias[u]             + bias[G3 + u];
    const float br_ = bias[U_DIM + u]     + bias[G3 + U_DIM + u];
    const float bhx = bias[2 * U_DIM + u];
    const float bhr = bias[G3 + 2 * U_DIM + u];

    const __bf16* pz = wlds + (0 * 16 + rc) * LDSK + (kg << 3);
    const __bf16* pr = wlds + (1 * 16 + rc) * LDSK + (kg << 3);
    const __bf16* ph = wlds + (2 * 16 + rc) * LDSK + (kg << 3);

    const float* xbase = x + (size_t)(row0 + rc) * (T_STEPS * F_DIM) + (kg << 3);
    const int hoff = (row0 + rc) * U_DIM + (kg << 3);

    for (int t = 0; t < T_STEPS; ++t) {
        f32x4 accZ  = {0.f, 0.f, 0.f, 0.f};
        f32x4 accR  = {0.f, 0.f, 0.f, 0.f};
        f32x4 accHX = {0.f, 0.f, 0.f, 0.f};
        f32x4 accHR = {0.f, 0.f, 0.f, 0.f};

        // ---- X phase: K=256, A from x (f32 -> bf16), B from LDS ----
        const float* ap = xbase + t * F_DIM;
#pragma unroll 4
        for (int k0 = 0; k0 < F_DIM; k0 += 32) {
            const float4 a0 = *(const float4*)(ap + k0);
            const float4 a1 = *(const float4*)(ap + k0 + 4);
            bf16x8 af;
            af[0] = (__bf16)a0.x; af[1] = (__bf16)a0.y;
            af[2] = (__bf16)a0.z; af[3] = (__bf16)a0.w;
            af[4] = (__bf16)a1.x; af[5] = (__bf16)a1.y;
            af[6] = (__bf16)a1.z; af[7] = (__bf16)a1.w;
            accZ  = __builtin_amdgcn_mfma_f32_16x16x32_bf16(af, *(const bf16x8*)(pz + k0), accZ,  0, 0, 0);
            accR  = __builtin_amdgcn_mfma_f32_16x16x32_bf16(af, *(const bf16x8*)(pr + k0), accR,  0, 0, 0);
            accHX = __builtin_amdgcn_mfma_f32_16x16x32_bf16(af, *(const bf16x8*)(ph + k0), accHX, 0, 0, 0);
        }

        // ---- H phase: K=1024, A from h(t-1), B from LDS (k offset 256) ----
        if (BF16H) {
            const __bf16* hp2 = ((t & 1) ? hbufB : hbufA) + hoff;
#pragma unroll 8
            for (int k = 0; k < U_DIM; k += 32) {
                const bf16x8 af = *(const bf16x8*)(hp2 + k);
                accZ  = __builtin_amdgcn_mfma_f32_16x16x32_bf16(af, *(const bf16x8*)(pz + F_DIM + k), accZ,  0, 0, 0);
                accR  = __builtin_amdgcn_mfma_f32_16x16x32_bf16(af, *(const bf16x8*)(pr + F_DIM + k), accR,  0, 0, 0);
                accHR = __builtin_amdgcn_mfma_f32_16x16x32_bf16(af, *(const bf16x8*)(ph + F_DIM + k), accHR, 0, 0, 0);
            }
        } else {
            const float* hb;
            int hs;
            if (t == 0) { hb = hidden; hs = U_DIM; }
            else        { hb = out + (size_t)(t - 1) * U_DIM; hs = T_STEPS * U_DIM; }
            const float* hp2 = hb + (size_t)(row0 + rc) * hs + (kg << 3);
#pragma unroll 8
            for (int k = 0; k < U_DIM; k += 32) {
                const float4 a0 = *(const float4*)(hp2 + k);
                const float4 a1 = *(const float4*)(hp2 + k + 4);
                bf16x8 af;
                af[0] = (__bf16)a0.x; af[1] = (__bf16)a0.y;
                af[2] = (__bf16)a0.z; af[3] = (__bf16)a0.w;
                af[4] = (__bf16)a1.x; af[5] = (__bf16)a1.y;
                af[6] = (__bf16)a1.z; af[7] = (__bf16)a1.w;
                accZ  = __builtin_amdgcn_mfma_f32_16x16x32_bf16(af, *(const bf16x8*)(pz + F_DIM + k), accZ,  0, 0, 0);
                accR  = __builtin_amdgcn_mfma_f32_16x16x32_bf16(af, *(const bf16x8*)(pr + F_DIM + k), accR,  0, 0, 0);
                accHR = __builtin_amdgcn_mfma_f32_16x16x32_bf16(af, *(const bf16x8*)(ph + F_DIM + k), accHR, 0, 0, 0);
            }
        }

        // ---- epilogue: gates f32, register carry, write out (+ bf16 h) ----
        __bf16* hdst = BF16H ? ((t & 1) ? hbufA : hbufB) : (__bf16*)nullptr;
#pragma unroll
        for (int j = 0; j < 4; ++j) {
            const int row = row0 + (kg << 2) + j;
            const float z  = sigmoidf_(accZ[j] + bz_);
            const float r  = sigmoidf_(accR[j] + br_);
            const float hh = tanhf_(accHX[j] + bhx + r * (accHR[j] + bhr));
            const float hn = z * hprev[j] + (1.f - z) * hh;
            hprev[j] = hn;
            out[((size_t)row * T_STEPS + t) * U_DIM + u] = hn;
            if (BF16H) hdst[(size_t)row * U_DIM + u] = (__bf16)hn;
            if (t == T_STEPS - 1)
                out[(size_t)B_ROWS * T_STEPS * U_DIM + (size_t)row * U_DIM + u] = hn;
        }

        grid.sync();
    }
}

extern "C" void kernel_launch(void* const* d_in, const int* in_sizes, int n_in,
                              void* d_out, int out_size, void* d_ws, size_t ws_size,
                              hipStream_t stream)
{
    const float* x      = (const float*)d_in[0];  // [64,512,256]
    const float* hidden = (const float*)d_in[1];  // [64,1024]
    const float* kernel = (const float*)d_in[2];  // [256,3072]
    const float* rker   = (const float*)d_in[3];  // [1024,3072]
    const float* bias   = (const float*)d_in[4];  // [2,3072]
    float* out = (float*)d_out;

    const size_t kt_el = (size_t)G3 * F_DIM;
    const size_t rt_el = (size_t)G3 * U_DIM;
    const size_t h_el  = (size_t)B_ROWS * U_DIM;
    __bf16* Kt = (__bf16*)d_ws;
    __bf16* Rt = Kt + kt_el;
    __bf16* hA = Rt + rt_el;
    __bf16* hB = hA + h_el;
    const bool useH = ws_size >= (kt_el + rt_el + 2 * h_el) * sizeof(__bf16);

    // Prep: transpose+convert weights to bf16 [col][k]  (runs once per call)
    hipLaunchKernelGGL(transpose_cvt_kernel, dim3(G3 / 32, F_DIM / 32), dim3(256),
                       0, stream, kernel, Kt, F_DIM);
    hipLaunchKernelGGL(transpose_cvt_kernel, dim3(G3 / 32, U_DIM / 32), dim3(256),
                       0, stream, rker, Rt, U_DIM);

    void* kx = (void*)&x;  void* kh = (void*)&hidden; void* kb = (void*)&bias;
    void* kK = (void*)&Kt; void* kR = (void*)&Rt;
    void* kA = (void*)&hA; void* kB2 = (void*)&hB;   void* ko = (void*)&out;
    void* args[8] = { kx, kh, kb, kK, kR, kA, kB2, ko };

    if (useH) {
        auto kfn = gru_persistent<true>;
        hipFuncSetAttribute((const void*)kfn,
                            hipFuncAttributeMaxDynamicSharedMemorySize, LDS_BYTES);
        hipLaunchCooperativeKernel(kfn, dim3(256), dim3(64), args, LDS_BYTES, stream);
    } else {
        auto kfn = gru_persistent<false>;
        hipFuncSetAttribute((const void*)kfn,
                            hipFuncAttributeMaxDynamicSharedMemorySize, LDS_BYTES);
        hipLaunchCooperativeKernel(kfn, dim3(256), dim3(64), args, LDS_BYTES, stream);
    }
}

// Round 3
// 3359.877 us; speedup vs baseline: 5.4232x; 5.4232x over previous
//
#include <hip/hip_runtime.h>

#define T_STEPS 512
#define B_ROWS  64
#define F_DIM   256
#define U_DIM   1024
#define G3      3072   // 3*U
#define KTOT    1280   // F + U
#define LDSK    1292   // KTOT + 12 bf16 pad -> row stride 2584B (bank shift 6/row, ~2-way max)
#define LDS_BYTES (3 * 16 * LDSK * 2)

typedef __bf16 bf16x8 __attribute__((ext_vector_type(8)));
typedef float  f32x4  __attribute__((ext_vector_type(4)));

__device__ __forceinline__ float sigmoidf_(float v) {
    return 1.f / (1.f + __expf(-v));
}
__device__ __forceinline__ float tanhf_(float v) {
    float e2 = __expf(2.f * v);
    return 1.f - 2.f / (e2 + 1.f);
}

// ---------------------------------------------------------------------------
// Transpose + cvt: src [Kdim][3072] f32  ->  dst [3072][Kdim] bf16
// ---------------------------------------------------------------------------
__global__ __launch_bounds__(256) void transpose_cvt_kernel(
    const float* __restrict__ src, __bf16* __restrict__ dst, int Kdim)
{
    __shared__ float tile[32][33];
    const int n0 = blockIdx.x * 32;
    const int k0 = blockIdx.y * 32;
    const int j  = threadIdx.x & 31;
    const int i0 = threadIdx.x >> 5;   // 0..7
#pragma unroll
    for (int s = 0; s < 4; ++s) {
        int i = i0 * 4 + s;
        tile[i][j] = src[(size_t)(k0 + i) * G3 + n0 + j];
    }
    __syncthreads();
#pragma unroll
    for (int s = 0; s < 4; ++s) {
        int i = i0 * 4 + s;
        dst[(size_t)(n0 + i) * Kdim + k0 + j] = (__bf16)tile[j][i];
    }
}

// ---------------------------------------------------------------------------
// Init: hidden f32 -> bf16 hbufA; reset flags. Grid 256 x 256.
// ---------------------------------------------------------------------------
__global__ __launch_bounds__(256) void init_kernel(
    const float* __restrict__ hidden, __bf16* __restrict__ hbufA,
    unsigned int* __restrict__ flags)
{
    const int i = blockIdx.x * 256 + threadIdx.x;
    if (i < B_ROWS * U_DIM) hbufA[i] = (__bf16)hidden[i];
    if (blockIdx.x == 0) flags[threadIdx.x] = 0u;
}

// ---------------------------------------------------------------------------
// Persistent GRU. Grid = 256 blocks x 64 threads (1 wave, 1 block/CU).
// Block bid: coltile c = bid & 63 (16 u's), rowtile rt = bid >> 6 (16 rows).
// Weights (3 gates x 16 u x 1280 k, bf16) live in LDS for all 512 steps.
// h exchange: group of 64 blocks sharing rt, via MALL (sc0 sc1 write-through
// stores + bypass loads) + per-block monotonic flags. No grid barrier.
// A-frag: lane holds A[row=l&15][k=(l>>4)*8+e];  B-frag: B[k][col=l&15];
// C/D: col=l&15, row=(l>>4)*4+j.  f32 carry stays in registers.
// ---------------------------------------------------------------------------
__global__ __launch_bounds__(64, 1) void gru_persistent(
    const float* __restrict__ x,       // [64][512][256] f32
    const float* __restrict__ hidden,  // [64][1024] f32
    const float* __restrict__ bias,    // [2][3072] f32
    const __bf16* __restrict__ Kt,     // [3072][256]
    const __bf16* __restrict__ Rt,     // [3072][1024]
    __bf16* __restrict__ hbufA,        // [64][1024] bf16
    __bf16* __restrict__ hbufB,        // [64][1024] bf16
    unsigned int* __restrict__ flags,  // [256]
    float* __restrict__ out)           // [64][512][1024] f32 (+ state tail)
{
    extern __shared__ __bf16 wlds[];   // [48][LDSK]
    const int lane = threadIdx.x & 63;
    const int rc   = lane & 15;
    const int kg   = lane >> 4;
    const int bid  = blockIdx.x;
    const int c    = bid & 63;
    const int rt   = bid >> 6;
    const int u    = (c << 4) + rc;
    const int row0 = rt << 4;

    // ---- stage weight slice into LDS (once) ----
    for (int i = lane; i < 48 * 160; i += 64) {
        const int rrow = i / 160;
        const int ch   = i - rrow * 160;          // 16B chunk index
        const int g    = rrow >> 4;
        const int ul   = rrow & 15;
        const int gu   = g * U_DIM + (c << 4) + ul;
        bf16x8 v;
        if (ch < 32) v = *(const bf16x8*)(Kt + (size_t)gu * F_DIM + ch * 8);
        else         v = *(const bf16x8*)(Rt + (size_t)gu * U_DIM + (ch - 32) * 8);
        *(bf16x8*)(wlds + rrow * LDSK + ch * 8) = v;
    }
    __syncthreads();

    // ---- per-thread invariants ----
    float hprev[4];
#pragma unroll
    for (int j = 0; j < 4; ++j)
        hprev[j] = hidden[(size_t)(row0 + (kg << 2) + j) * U_DIM + u];

    const float bz_ = bias[u]             + bias[G3 + u];
    const float br_ = bias[U_DIM + u]     + bias[G3 + U_DIM + u];
    const float bhx = bias[2 * U_DIM + u];
    const float bhr = bias[G3 + 2 * U_DIM + u];

    const __bf16* pz = wlds + (0 * 16 + rc) * LDSK + (kg << 3);
    const __bf16* pr = wlds + (1 * 16 + rc) * LDSK + (kg << 3);
    const __bf16* ph = wlds + (2 * 16 + rc) * LDSK + (kg << 3);

    const float* xbase = x + (size_t)(row0 + rc) * (T_STEPS * F_DIM) + (kg << 3);
    const unsigned int* fp = flags + (rt << 6) + lane;  // my group's 64 flags

    for (int t = 0; t < T_STEPS; ++t) {
        f32x4 accZ  = {0.f, 0.f, 0.f, 0.f};
        f32x4 accR  = {0.f, 0.f, 0.f, 0.f};
        f32x4 accHX = {0.f, 0.f, 0.f, 0.f};
        f32x4 accHR = {0.f, 0.f, 0.f, 0.f};

        // ---- X phase (independent of h; runs before the flag wait) ----
        const float* ap = xbase + t * F_DIM;
#pragma unroll
        for (int k0 = 0; k0 < F_DIM; k0 += 32) {
            const float4 a0 = *(const float4*)(ap + k0);
            const float4 a1 = *(const float4*)(ap + k0 + 4);
            bf16x8 af;
            af[0] = (__bf16)a0.x; af[1] = (__bf16)a0.y;
            af[2] = (__bf16)a0.z; af[3] = (__bf16)a0.w;
            af[4] = (__bf16)a1.x; af[5] = (__bf16)a1.y;
            af[6] = (__bf16)a1.z; af[7] = (__bf16)a1.w;
            accZ  = __builtin_amdgcn_mfma_f32_16x16x32_bf16(af, *(const bf16x8*)(pz + k0), accZ,  0, 0, 0);
            accR  = __builtin_amdgcn_mfma_f32_16x16x32_bf16(af, *(const bf16x8*)(pr + k0), accR,  0, 0, 0);
            accHX = __builtin_amdgcn_mfma_f32_16x16x32_bf16(af, *(const bf16x8*)(ph + k0), accHX, 0, 0, 0);
        }

        // ---- group barrier: wait for all 64 siblings to have stored h(t-1) ----
        if (t > 0) {
            const unsigned int target = (unsigned int)t;
            for (;;) {
                unsigned int f;
                asm volatile("global_load_dword %0, %1, off sc0 sc1\n\t"
                             "s_waitcnt vmcnt(0)"
                             : "=v"(f) : "v"(fp) : "memory");
                if (__all((int)(f >= target))) break;
                __builtin_amdgcn_s_sleep(2);
            }
        }

        // ---- load h(t-1) A-fragments straight to registers (MALL bypass) ----
        const __bf16* hread = (t & 1) ? hbufB : hbufA;
        const __bf16* hbase = hread + (size_t)(row0 + rc) * U_DIM + (kg << 3);
        bf16x8 hfrag[32];
#define HLOAD(idx, lit)                                                     \
        asm volatile("global_load_dwordx4 %0, %1, off offset:" lit " sc0 sc1" \
                     : "=v"(hfrag[idx]) : "v"(hbase) : "memory");
        HLOAD(0,"0")     HLOAD(1,"64")    HLOAD(2,"128")   HLOAD(3,"192")
        HLOAD(4,"256")   HLOAD(5,"320")   HLOAD(6,"384")   HLOAD(7,"448")
        HLOAD(8,"512")   HLOAD(9,"576")   HLOAD(10,"640")  HLOAD(11,"704")
        HLOAD(12,"768")  HLOAD(13,"832")  HLOAD(14,"896")  HLOAD(15,"960")
        HLOAD(16,"1024") HLOAD(17,"1088") HLOAD(18,"1152") HLOAD(19,"1216")
        HLOAD(20,"1280") HLOAD(21,"1344") HLOAD(22,"1408") HLOAD(23,"1472")
        HLOAD(24,"1536") HLOAD(25,"1600") HLOAD(26,"1664") HLOAD(27,"1728")
        HLOAD(28,"1792") HLOAD(29,"1856") HLOAD(30,"1920") HLOAD(31,"1984")
#undef HLOAD
        asm volatile("s_waitcnt vmcnt(0)" ::: "memory");
        __builtin_amdgcn_sched_barrier(0);

        // ---- H phase: K=1024, A from registers, B from LDS (k offset 256) ----
#pragma unroll
        for (int ki = 0; ki < 32; ++ki) {
            const bf16x8 af = hfrag[ki];
            accZ  = __builtin_amdgcn_mfma_f32_16x16x32_bf16(af, *(const bf16x8*)(pz + F_DIM + ki * 32), accZ,  0, 0, 0);
            accR  = __builtin_amdgcn_mfma_f32_16x16x32_bf16(af, *(const bf16x8*)(pr + F_DIM + ki * 32), accR,  0, 0, 0);
            accHR = __builtin_amdgcn_mfma_f32_16x16x32_bf16(af, *(const bf16x8*)(ph + F_DIM + ki * 32), accHR, 0, 0, 0);
        }

        // ---- epilogue: gates f32, register carry, stores ----
        __bf16* hwrite = (t & 1) ? hbufA : hbufB;
#pragma unroll
        for (int j = 0; j < 4; ++j) {
            const int row = row0 + (kg << 2) + j;
            const float z  = sigmoidf_(accZ[j] + bz_);
            const float r  = sigmoidf_(accR[j] + br_);
            const float hh = tanhf_(accHX[j] + bhx + r * (accHR[j] + bhr));
            const float hn = z * hprev[j] + (1.f - z) * hh;
            hprev[j] = hn;
            out[((size_t)row * T_STEPS + t) * U_DIM + u] = hn;
            const __bf16 hb = (__bf16)hn;
            const unsigned int uv = (unsigned int)__builtin_bit_cast(unsigned short, hb);
            asm volatile("global_store_short %0, %1, off sc0 sc1"
                         :: "v"(hwrite + (size_t)row * U_DIM + u), "v"(uv) : "memory");
            if (t == T_STEPS - 1)
                out[(size_t)B_ROWS * T_STEPS * U_DIM + (size_t)row * U_DIM + u] = hn;
        }

        // ---- publish: h(t) visible at MALL, then flag = t+1 ----
        asm volatile("s_waitcnt vmcnt(0)" ::: "memory");
        if (lane == 0) {
            const unsigned int tv = (unsigned int)(t + 1);
            asm volatile("global_store_dword %0, %1, off sc0 sc1"
                         :: "v"(flags + bid), "v"(tv) : "memory");
        }
    }
}

extern "C" void kernel_launch(void* const* d_in, const int* in_sizes, int n_in,
                              void* d_out, int out_size, void* d_ws, size_t ws_size,
                              hipStream_t stream)
{
    const float* x      = (const float*)d_in[0];  // [64,512,256]
    const float* hidden = (const float*)d_in[1];  // [64,1024]
    const float* kernel = (const float*)d_in[2];  // [256,3072]
    const float* rker   = (const float*)d_in[3];  // [1024,3072]
    const float* bias   = (const float*)d_in[4];  // [2,3072]
    float* out = (float*)d_out;

    const size_t kt_el = (size_t)G3 * F_DIM;
    const size_t rt_el = (size_t)G3 * U_DIM;
    const size_t h_el  = (size_t)B_ROWS * U_DIM;
    __bf16* Kt = (__bf16*)d_ws;
    __bf16* Rt = Kt + kt_el;
    __bf16* hA = Rt + rt_el;
    __bf16* hB = hA + h_el;
    unsigned int* flags = (unsigned int*)(hB + h_el);

    hipLaunchKernelGGL(transpose_cvt_kernel, dim3(G3 / 32, F_DIM / 32), dim3(256),
                       0, stream, kernel, Kt, F_DIM);
    hipLaunchKernelGGL(transpose_cvt_kernel, dim3(G3 / 32, U_DIM / 32), dim3(256),
                       0, stream, rker, Rt, U_DIM);
    hipLaunchKernelGGL(init_kernel, dim3(256), dim3(256), 0, stream,
                       hidden, hA, flags);

    void* kx = (void*)&x;  void* kh = (void*)&hidden; void* kb = (void*)&bias;
    void* kK = (void*)&Kt; void* kR = (void*)&Rt;
    void* kA = (void*)&hA; void* kB2 = (void*)&hB;
    void* kF = (void*)&flags; void* ko = (void*)&out;
    void* args[9] = { kx, kh, kb, kK, kR, kA, kB2, kF, ko };

    auto kfn = gru_persistent;
    hipFuncSetAttribute((const void*)kfn,
                        hipFuncAttributeMaxDynamicSharedMemorySize, LDS_BYTES);
    hipLaunchCooperativeKernel(kfn, dim3(256), dim3(64), args, LDS_BYTES, stream);
}